// Round 7
// baseline (19.804 us; speedup 1.0000x reference)
//
#include <hip/hip_runtime.h>
#include <math.h>

// Problem constants: B=32, H=100, C=50, D=400, HID=400
#define B_   32
#define H_   100
#define C_   50
#define D_   400
#define HID_ 400
#define NTHREADS 1024

#define NEGF (-3.4028234663852886e38f)  // finfo(float32).min

// Algebraic collapse (verified R1-R6, absmax 1.5e-5):
//   weights[b,h] = softmax_h(mask ? hist[b,h]·u : finfo.min), u = W1[D:,:]@w2
//   out[b,c,:]   = mask_cand[b,c] ? sum_h w[b,h]*hist[b,h,:] : 0
//
// R6 post-mortem: 2 dependent kernels each pay ramp/drain + hist is read from
// HBM twice + s_part round-trips L3. This round: ONE dispatch, one block per
// b (32 x 1024). Each block computes u REDUNDANTLY (W1h is L2-shared by the
// 4 blocks of an XCD; total L2 traffic equals the old replication scheme), so
// no cross-block dependency and no grid sync (R4 showed atomics cost ~28us).
// Every phase is parallel across 64 16-lane groups / 16 waves; all load
// rounds are independent (R1's serial-chain mistake avoided).

__device__ __forceinline__ float dot4(float4 a, float4 b) {
    return fmaf(a.x, b.x, fmaf(a.y, b.y, fmaf(a.z, b.z, a.w * b.w)));
}

__global__ __launch_bounds__(NTHREADS)
void fused_b(const float* __restrict__ hist,      // (B,H,D)
             const int*   __restrict__ mask_hist, // (B,H)
             const int*   __restrict__ mask_cand, // (B,C)
             const float* __restrict__ W1,        // (2D,HID)
             const float* __restrict__ w2,        // (HID)
             float* __restrict__ out)             // (B,C,D)
{
    __shared__ float4 u4_lds[D_ / 4];      // u, 100 float4 (16B-aligned)
    __shared__ float  s_lds[H_];           // masked scores
    __shared__ float  w_lds[H_];           // softmax weights
    __shared__ float4 part_lds[1000];      // V partials [col4*10 + hg], 16 KB
    __shared__ float4 uv4_lds[100];        // final user vector

    const int b    = blockIdx.x;
    const int tid  = threadIdx.x;
    const int lane = tid & 63;
    const int wave = tid >> 6;             // 0..15
    const int l16  = tid & 15;
    const int g    = tid >> 4;             // 16-lane group id, 0..63

    const float4* w24 = (const float4*)w2;                            // 100 f4
    const float4* h4  = (const float4*)(hist + (size_t)b * H_ * D_);  // 100 f4/row

    // ---- Phase U: u[d] = dot(W1[D+d,:], w2), one row per 16-lane group ----
    #pragma unroll 2
    for (int p = 0; p < 7; p++) {
        const int d = g + 64 * p;
        if (d < D_) {
            const float4* row4 = (const float4*)(W1 + (size_t)(D_ + d) * HID_);
            float acc = 0.f;
            #pragma unroll
            for (int j = 0; j < 6; j++)          // cols l16+16j <= 95
                acc += dot4(row4[l16 + 16 * j], w24[l16 + 16 * j]);
            if (l16 < 4)                          // tail cols 96..99
                acc += dot4(row4[96 + l16], w24[96 + l16]);
            #pragma unroll
            for (int off = 8; off; off >>= 1)     // reduce within 16-lane group
                acc += __shfl_xor(acc, off, 64);
            if (l16 == 0) ((float*)u4_lds)[d] = acc;
        }
    }
    __syncthreads();

    // ---- Phase S: s[h] = mask ? hist[b,h,:]·u : NEG, one row per group ----
    #pragma unroll
    for (int p = 0; p < 2; p++) {
        const int h = g + 64 * p;
        if (h < H_) {
            const float4* row4 = h4 + (size_t)h * 100;
            float acc = 0.f;
            #pragma unroll
            for (int j = 0; j < 6; j++)
                acc += dot4(row4[l16 + 16 * j], u4_lds[l16 + 16 * j]);
            if (l16 < 4)
                acc += dot4(row4[96 + l16], u4_lds[96 + l16]);
            #pragma unroll
            for (int off = 8; off; off >>= 1)
                acc += __shfl_xor(acc, off, 64);
            if (l16 == 0)
                s_lds[h] = mask_hist[b * H_ + h] ? acc : NEGF;
        }
    }
    __syncthreads();

    // ---- Softmax (wave 0 only; others wait at the barrier) ----
    if (wave == 0) {
        const float s0 = s_lds[lane];
        const float s1 = (lane < 36) ? s_lds[64 + lane] : -INFINITY;
        float m = fmaxf(s0, s1);
        #pragma unroll
        for (int off = 32; off; off >>= 1) m = fmaxf(m, __shfl_xor(m, off, 64));
        const float e0 = expf(s0 - m);
        const float e1 = (lane < 36) ? expf(s1 - m) : 0.f;
        float ps = e0 + e1;
        #pragma unroll
        for (int off = 32; off; off >>= 1) ps += __shfl_xor(ps, off, 64);
        const float inv = 1.f / ps;
        w_lds[lane] = e0 * inv;
        if (lane < 36) w_lds[64 + lane] = e1 * inv;
    }
    __syncthreads();

    // ---- Phase V: uv[col4] = sum_h w[h]*hist4[h][col4]; 100 col4 x 10 hg ----
    if (tid < 1000) {
        const int hg   = tid / 100;         // h-group 0..9 (10 h each)
        const int col4 = tid % 100;         // consecutive tid -> coalesced
        float4 acc = make_float4(0.f, 0.f, 0.f, 0.f);
        #pragma unroll
        for (int i = 0; i < 10; i++) {
            const int h = hg * 10 + i;
            const float  w = w_lds[h];
            const float4 a = h4[(size_t)h * 100 + col4];   // L2-hot (phase S)
            acc.x = fmaf(w, a.x, acc.x);
            acc.y = fmaf(w, a.y, acc.y);
            acc.z = fmaf(w, a.z, acc.z);
            acc.w = fmaf(w, a.w, acc.w);
        }
        part_lds[col4 * 10 + hg] = acc;
    }
    __syncthreads();
    if (tid < 100) {
        float4 s = make_float4(0.f, 0.f, 0.f, 0.f);
        #pragma unroll
        for (int i = 0; i < 10; i++) {
            float4 p = part_lds[tid * 10 + i];
            s.x += p.x; s.y += p.y; s.z += p.z; s.w += p.w;
        }
        uv4_lds[tid] = s;
    }
    __syncthreads();

    // ---- Phase O: out[b,c,:] = mask_cand[b,c] ? uv : 0 ; 5000 f4 stores ----
    const int* mc = mask_cand + b * C_;
    float4* outb = (float4*)(out + (size_t)b * C_ * D_);   // 50*100 f4
    const float4 z = make_float4(0.f, 0.f, 0.f, 0.f);
    #pragma unroll
    for (int k = 0; k < 5; k++) {
        const int idx = tid + NTHREADS * k;
        if (idx < C_ * 100) {
            const int c    = idx / 100;
            const int col4 = idx % 100;
            outb[idx] = mc[c] ? uv4_lds[col4] : z;
        }
    }
}

extern "C" void kernel_launch(void* const* d_in, const int* in_sizes, int n_in,
                              void* d_out, int out_size, void* d_ws, size_t ws_size,
                              hipStream_t stream) {
    // inputs: 0 hist(B,H,D) f32, 1 cand [unused], 2 mask_hist(B,H) i32,
    //         3 mask_cand(B,C) i32, 4 W1(2D,HID) f32, 5 b1 [unused],
    //         6 w2(HID) f32, 7 b2 [unused]
    const float* hist      = (const float*)d_in[0];
    const int*   mask_hist = (const int*)d_in[2];
    const int*   mask_cand = (const int*)d_in[3];
    const float* W1        = (const float*)d_in[4];
    const float* w2        = (const float*)d_in[6];
    float* out = (float*)d_out;

    fused_b<<<B_, NTHREADS, 0, stream>>>(hist, mask_hist, mask_cand, W1, w2, out);
}

// Round 8
// 18.602 us; speedup vs baseline: 1.0646x; 1.0646x over previous
//
#include <hip/hip_runtime.h>
#include <math.h>

// Problem constants: B=32, H=100, C=50, D=400, HID=400
#define B_   32
#define H_   100
#define C_   50
#define D_   400
#define HID_ 400

#define NEGF (-3.4028234663852886e38f)  // finfo(float32).min

// Algebraic collapse (verified R1-R7, absmax 1.5e-5):
//   weights[b,h] = softmax_h(mask ? hist[b,h]·u : finfo.min), u = W1[D:,:]@w2
//   out[b,c,:]   = mask_cand[b,c] ? sum_h w[b,h]*hist[b,h,:] : 0
//
// Evidence so far:
//   R4: agent-scope atomic grid sync = +28us. Dependencies go through
//       dispatch boundaries (~0.3us), never through atomics.
//   R7: per-BLOCK redundant u (640KB W1h through each CU's L1) = +5..10us.
//       Heavy shared reads must not be replicated per-CU.
//   R6 (best, 14.7us): paid hist twice from HBM + s_part L3 round-trip.
// This round: K1 computes u once (640KB total). K2 = one block per b:
// hist[b] read once from HBM for scores (prefetch hoisted above the u
// barrier), re-read L2-hot for the weighted sum, masked broadcast store.

__device__ __forceinline__ float dot4(float4 a, float4 b) {
    return fmaf(a.x, b.x, fmaf(a.y, b.y, fmaf(a.z, b.z, a.w * b.w)));
}

// ---- K1: u[row] = dot(W1[D+row,:], w2). One wave per row. grid=50x512 ----
__global__ __launch_bounds__(512)
void k1_u(const float* __restrict__ W1, const float* __restrict__ w2,
          float* __restrict__ u) {
    const int row  = blockIdx.x * 8 + (threadIdx.x >> 6);   // 0..399
    const int lane = threadIdx.x & 63;
    const float4* r4 = (const float4*)(W1 + (size_t)(D_ + row) * HID_);
    const float4* w4 = (const float4*)w2;
    float4 a0 = r4[lane], b0 = w4[lane];
    float acc = dot4(a0, b0);
    if (lane < 36) {                    // 100 float4 per row = 64 + 36
        float4 a1 = r4[64 + lane], b1 = w4[64 + lane];
        acc += dot4(a1, b1);
    }
    #pragma unroll
    for (int off = 32; off; off >>= 1) acc += __shfl_xor(acc, off, 64);
    if (lane == 0) u[row] = acc;
}

// ---- K2: per-b fused scores + softmax + weighted sum + masked stores.
//      grid = 32, block = 1024 ----
__global__ __launch_bounds__(1024)
void k2_fused(const float* __restrict__ hist,      // (B,H,D)
              const float* __restrict__ u,         // (D)
              const int*   __restrict__ mask_hist, // (B,H)
              const int*   __restrict__ mask_cand, // (B,C)
              float* __restrict__ out)             // (B,C,D)
{
    __shared__ float4 u4_lds[100];
    __shared__ float  s_lds[H_];
    __shared__ float  w_lds[H_];
    __shared__ float4 part_lds[1000];   // [col4*10 + hg], 16 KB
    __shared__ float4 uv4_lds[100];

    const int b    = blockIdx.x;
    const int tid  = threadIdx.x;
    const int lane = tid & 63;
    const int wave = tid >> 6;          // 0..15
    const int l16  = tid & 15;
    const int g    = tid >> 4;          // 16-lane group id, 0..63

    const float4* h4 = (const float4*)(hist + (size_t)b * H_ * D_); // 100 f4/row

    // ---- u -> LDS (first 100 threads; issued before the prefetch burst) ----
    if (tid < 100) u4_lds[tid] = ((const float4*)u)[tid];

    // ---- S-phase hist prefetch (independent of u): group g owns rows g,g+64 ----
    const int row0 = g;                 // < 100 always
    const int row1 = g + 64;            // < 100 only for g < 36
    float4 ha0[7], ha1[7];
    #pragma unroll
    for (int j = 0; j < 6; j++)
        ha0[j] = h4[(size_t)row0 * 100 + l16 + 16 * j];
    ha0[6] = (l16 < 4) ? h4[(size_t)row0 * 100 + 96 + l16]
                       : make_float4(0.f, 0.f, 0.f, 0.f);
    if (row1 < H_) {
        #pragma unroll
        for (int j = 0; j < 6; j++)
            ha1[j] = h4[(size_t)row1 * 100 + l16 + 16 * j];
        ha1[6] = (l16 < 4) ? h4[(size_t)row1 * 100 + 96 + l16]
                           : make_float4(0.f, 0.f, 0.f, 0.f);
    }
    __syncthreads();                    // u4_lds ready

    // ---- S dots: 16-lane-group reduction per row ----
    {
        float acc = 0.f;
        #pragma unroll
        for (int j = 0; j < 6; j++) acc += dot4(ha0[j], u4_lds[l16 + 16 * j]);
        if (l16 < 4) acc += dot4(ha0[6], u4_lds[96 + l16]);
        #pragma unroll
        for (int off = 8; off; off >>= 1) acc += __shfl_xor(acc, off, 64);
        if (l16 == 0) s_lds[row0] = mask_hist[b * H_ + row0] ? acc : NEGF;
    }
    if (row1 < H_) {
        float acc = 0.f;
        #pragma unroll
        for (int j = 0; j < 6; j++) acc += dot4(ha1[j], u4_lds[l16 + 16 * j]);
        if (l16 < 4) acc += dot4(ha1[6], u4_lds[96 + l16]);
        #pragma unroll
        for (int off = 8; off; off >>= 1) acc += __shfl_xor(acc, off, 64);
        if (l16 == 0) s_lds[row1] = mask_hist[b * H_ + row1] ? acc : NEGF;
    }
    __syncthreads();

    // ---- Softmax over s_lds[0..99] (wave 0 publishes weights) ----
    if (wave == 0) {
        const float s0 = s_lds[lane];
        const float s1 = (lane < 36) ? s_lds[64 + lane] : -INFINITY;
        float m = fmaxf(s0, s1);
        #pragma unroll
        for (int off = 32; off; off >>= 1) m = fmaxf(m, __shfl_xor(m, off, 64));
        const float e0 = expf(s0 - m);
        const float e1 = (lane < 36) ? expf(s1 - m) : 0.f;
        float ps = e0 + e1;
        #pragma unroll
        for (int off = 32; off; off >>= 1) ps += __shfl_xor(ps, off, 64);
        const float inv = 1.f / ps;
        w_lds[lane] = e0 * inv;
        if (lane < 36) w_lds[64 + lane] = e1 * inv;
    }
    __syncthreads();

    // ---- V phase: uv[col4] = sum_h w[h]*hist4[h][col4]; L2-hot re-read ----
    if (tid < 1000) {
        const int hg   = tid / 100;     // 0..9 (10 h each)
        const int col4 = tid % 100;     // consecutive tid -> coalesced
        float4 acc = make_float4(0.f, 0.f, 0.f, 0.f);
        #pragma unroll
        for (int i = 0; i < 10; i++) {
            const int h = hg * 10 + i;
            const float  w = w_lds[h];
            const float4 a = h4[(size_t)h * 100 + col4];
            acc.x = fmaf(w, a.x, acc.x);
            acc.y = fmaf(w, a.y, acc.y);
            acc.z = fmaf(w, a.z, acc.z);
            acc.w = fmaf(w, a.w, acc.w);
        }
        part_lds[col4 * 10 + hg] = acc;
    }
    __syncthreads();
    if (tid < 100) {
        float4 s = make_float4(0.f, 0.f, 0.f, 0.f);
        #pragma unroll
        for (int i = 0; i < 10; i++) {
            float4 p = part_lds[tid * 10 + i];
            s.x += p.x; s.y += p.y; s.z += p.z; s.w += p.w;
        }
        uv4_lds[tid] = s;
    }
    __syncthreads();

    // ---- O phase: out[b,c,:] = mask_cand[b,c] ? uv : 0 ; 5000 f4 stores ----
    const int* mc = mask_cand + b * C_;
    float4* outb = (float4*)(out + (size_t)b * C_ * D_);
    const float4 z = make_float4(0.f, 0.f, 0.f, 0.f);
    #pragma unroll
    for (int k = 0; k < 5; k++) {
        const int idx = tid + 1024 * k;
        if (idx < C_ * 100) {
            const int c    = idx / 100;
            const int col4 = idx % 100;
            outb[idx] = mc[c] ? uv4_lds[col4] : z;
        }
    }
}

extern "C" void kernel_launch(void* const* d_in, const int* in_sizes, int n_in,
                              void* d_out, int out_size, void* d_ws, size_t ws_size,
                              hipStream_t stream) {
    // inputs: 0 hist(B,H,D) f32, 1 cand [unused], 2 mask_hist(B,H) i32,
    //         3 mask_cand(B,C) i32, 4 W1(2D,HID) f32, 5 b1 [unused],
    //         6 w2(HID) f32, 7 b2 [unused]
    const float* hist      = (const float*)d_in[0];
    const int*   mask_hist = (const int*)d_in[2];
    const int*   mask_cand = (const int*)d_in[3];
    const float* W1        = (const float*)d_in[4];
    const float* w2        = (const float*)d_in[6];
    float* out = (float*)d_out;

    float* u = (float*)d_ws;    // 400 floats scratch

    k1_u    <<<D_ / 8, 512,  0, stream>>>(W1, w2, u);
    k2_fused<<<B_,     1024, 0, stream>>>(hist, u, mask_hist, mask_cand, out);
}